// Round 7
// baseline (325.081 us; speedup 1.0000x reference)
//
#include <hip/hip_runtime.h>
#include <hip/hip_fp16.h>

typedef float fv4 __attribute__((ext_vector_type(4)));
using hf8   = __attribute__((ext_vector_type(8))) _Float16;  // 8 fp16 = 4 VGPRs (MFMA A/B frag)
using f32x4 = __attribute__((ext_vector_type(4))) float;     // MFMA C/D frag
using u32x4 = __attribute__((ext_vector_type(4))) unsigned;
using u32x2 = __attribute__((ext_vector_type(2))) unsigned;

#define HDIM 64

// fp32 -> fp16 bits (RNE)
__device__ __forceinline__ unsigned short f16r(float f) {
    return __half_as_ushort(__float2half(f));
}
__device__ __forceinline__ float hs2f(unsigned short s) {
    return __half2float(__ushort_as_half(s));
}
// packed fp16: relu(u+v) on 2 channels in one reg (v_pk_add_f16 + v_pk_max_f16)
__device__ __forceinline__ unsigned addrelu2(unsigned ua, unsigned va) {
    unsigned s, r;
    asm("v_pk_add_f16 %0, %1, %2" : "=v"(s) : "v"(ua), "v"(va));
    asm("v_pk_max_f16 %0, %1, 0" : "=v"(r) : "v"(s));
    return r;
}

// ---------------------------------------------------------------------------
// pre1 (+ fused prep + label histogram): blocks < mainBlocks do
//   u = [x|pos] @ (W1a - W1b) + b1 ; v = [x|pos] @ W1b   (D = 19)
// blocks >= mainBlocks: weight split hi/lo + qcnt label histogram.
// (qsums/qcnt zeroed by hipMemsetAsync BEFORE this kernel -- in-kernel
//  zeroing would race the histogram atomics across blocks.)
// ---------------------------------------------------------------------------
__global__ void pre1_kernel(
    const float* __restrict__ x, const float* __restrict__ pos,
    const float* __restrict__ W1, const float* __restrict__ b1,
    unsigned short* __restrict__ U, unsigned short* __restrict__ V, int N,
    int mainBlocks,
    const float* __restrict__ W2a, const float* __restrict__ W2b,
    const float* __restrict__ W1c,
    unsigned short* __restrict__ hiA, unsigned short* __restrict__ loA,
    unsigned short* __restrict__ hiB, unsigned short* __restrict__ loB,
    unsigned short* __restrict__ wph, unsigned short* __restrict__ wpl,
    const int* __restrict__ labels, int* __restrict__ qcnt)
{
    if ((int)blockIdx.x >= mainBlocks) {
        int idx = (blockIdx.x - mainBlocks) * 256 + threadIdx.x;
        if (idx < 4096) {
            int j = idx >> 6, c = idx & 63;
            float w = W2a[idx];
            unsigned short h = f16r(w);
            unsigned short l = f16r(w - hs2f(h));
            hiA[c * 64 + j] = h; loA[c * 64 + j] = l;
            w = W2b[idx];
            h = f16r(w);
            l = f16r(w - hs2f(h));
            hiB[c * 64 + j] = h; loB[c * 64 + j] = l;
        }
        if (idx < 8192) {
            int d = idx & 63, cp = idx >> 6;
            float w = (cp < 64) ? (W1c[d * 64 + cp] - W1c[(d + 64) * 64 + cp])
                                : W1c[(d + 64) * 64 + (cp - 64)];
            unsigned short h = f16r(w);
            unsigned short l = f16r(w - hs2f(h));
            wph[cp * 64 + d] = h;
            wpl[cp * 64 + d] = l;
        }
        // label histogram -> qcnt (8192 threads grid-stride over N)
        {
            __shared__ int lh[8];
            int loc[8] = {0, 0, 0, 0, 0, 0, 0, 0};
            for (int n = idx; n < N; n += 8192) {
                int l = labels[n];
#pragma unroll
                for (int r = 0; r < 8; ++r) loc[r] += (l == r) ? 1 : 0;
            }
            if (threadIdx.x < 8) lh[threadIdx.x] = 0;
            __syncthreads();
#pragma unroll
            for (int r = 0; r < 8; ++r) if (loc[r]) atomicAdd(&lh[r], loc[r]);
            __syncthreads();
            if (threadIdx.x < 8) atomicAdd(&qcnt[threadIdx.x], lh[threadIdx.x]);
        }
        return;
    }

    int lane = threadIdx.x & 63;
    int gw   = (blockIdx.x * blockDim.x + threadIdx.x) >> 6;
    int tw   = (mainBlocks * blockDim.x) >> 6;

    float wd[19], wb[19];
#pragma unroll
    for (int d = 0; d < 19; ++d) {
        float a = W1[d * HDIM + lane];
        float b = W1[(d + 19) * HDIM + lane];
        wd[d] = a - b;
        wb[d] = b;
    }
    float bb = b1[lane];

    for (int n = gw; n < N; n += tw) {
        float su = 0.f, sv = 0.f;
#pragma unroll
        for (int d4 = 0; d4 < 4; ++d4) {
            fv4 h4 = *(const fv4*)&x[(size_t)n * 16 + 4 * d4];
#pragma unroll
            for (int k = 0; k < 4; ++k) {
                su += h4[k] * wd[4 * d4 + k];
                sv += h4[k] * wb[4 * d4 + k];
            }
        }
#pragma unroll
        for (int d = 0; d < 3; ++d) {
            float h = pos[(size_t)n * 3 + d];
            su += h * wd[16 + d];
            sv += h * wb[16 + d];
        }
        U[(size_t)n * HDIM + lane] = f16r(su + bb);
        V[(size_t)n * HDIM + lane] = f16r(sv);
    }
}

// ---------------------------------------------------------------------------
// pre_mfma (conv2 layer-1): [N x 64] @ [64 x 128] on MFMA (fp16).
// OPERAND-SWAPPED: mfma(W, h) so D row = channel, D col = node. Per lane the
// 4 acc elements of one nt are 4 CONSECUTIVE channels of node (base+m)
// -> 8 x 8B stores per tile instead of 32 x 2B. Input frag loads unchanged.
// ---------------------------------------------------------------------------
__global__ __launch_bounds__(256, 2) void pre_mfma_kernel(
    const unsigned short* __restrict__ h,     // fp16 N x 64
    const unsigned short* __restrict__ Whi,   // fp16 [c' 0..127][d 0..63]
    const unsigned short* __restrict__ Wlo,
    const float* __restrict__ b1,
    unsigned short* __restrict__ U, unsigned short* __restrict__ V, int nTiles)
{
    int lane = threadIdx.x & 63;
    int quad = lane >> 4;
    int m    = lane & 15;
    int gw   = (blockIdx.x * blockDim.x + threadIdx.x) >> 6;
    int tw   = (gridDim.x * blockDim.x) >> 6;

    hf8 Bh[8][2], Bl[8][2];
#pragma unroll
    for (int nt = 0; nt < 8; ++nt)
#pragma unroll
        for (int ks = 0; ks < 2; ++ks) {
            int off = (nt * 16 + m) * 64 + ks * 32 + quad * 8;
            Bh[nt][ks] = *(const hf8*)&Whi[off];
            Bl[nt][ks] = *(const hf8*)&Wlo[off];
        }
    float bias[16];        // [nt][r] = b1[nt*16 + quad*4 + r]
#pragma unroll
    for (int nt = 0; nt < 4; ++nt)
#pragma unroll
        for (int r = 0; r < 4; ++r)
            bias[nt * 4 + r] = b1[nt * 16 + quad * 4 + r];

    for (int t = gw; t < nTiles; t += tw) {
        int base = t * 16;
        hf8 A[2];
#pragma unroll
        for (int ks = 0; ks < 2; ++ks)
            A[ks] = *(const hf8*)&h[(size_t)(base + m) * HDIM + ks * 32 + quad * 8];

        f32x4 acc[8] = {{0,0,0,0},{0,0,0,0},{0,0,0,0},{0,0,0,0},
                        {0,0,0,0},{0,0,0,0},{0,0,0,0},{0,0,0,0}};
#pragma unroll
        for (int ks = 0; ks < 2; ++ks)
#pragma unroll
            for (int nt = 0; nt < 8; ++nt) {
                acc[nt] = __builtin_amdgcn_mfma_f32_16x16x32_f16(Bl[nt][ks], A[ks], acc[nt], 0, 0, 0);
                acc[nt] = __builtin_amdgcn_mfma_f32_16x16x32_f16(Bh[nt][ks], A[ks], acc[nt], 0, 0, 0);
            }

        // lane (quad,m): acc[nt][r] = out[node=base+m][channel nt*16+quad*4+r]
#pragma unroll
        for (int nt = 0; nt < 8; ++nt) {
            unsigned short* __restrict__ dst = (nt < 4) ? U : V;
            int c0 = (nt & 3) * 16 + quad * 4;
            float a0 = acc[nt][0] + ((nt < 4) ? bias[nt * 4 + 0] : 0.f);
            float a1 = acc[nt][1] + ((nt < 4) ? bias[nt * 4 + 1] : 0.f);
            float a2 = acc[nt][2] + ((nt < 4) ? bias[nt * 4 + 2] : 0.f);
            float a3 = acc[nt][3] + ((nt < 4) ? bias[nt * 4 + 3] : 0.f);
            u32x2 pk;
            pk[0] = (unsigned)f16r(a0) | ((unsigned)f16r(a1) << 16);
            pk[1] = (unsigned)f16r(a2) | ((unsigned)f16r(a3) << 16);
            *(u32x2*)&dst[(size_t)(base + m) * HDIM + c0] = pk;
        }
    }
}

// ---------------------------------------------------------------------------
// edge_mfma<POOL>: out[t][c] = relu( max_{16 edges}( relu(u[t]+v[src]) @ W2 )[c] + b2[c] )
// 64 nodes/block (4 tiles/wave), depth-2 pipeline:
//   issue A,B -> fold A -> issue C -> fold B -> issue D -> fold C -> fold D
// (8 gathers always in flight; <=2.5 static-named buffer sets live -> no
// scratch). W2 hi/lo in swizzled LDS; block's 64 U rows in LDS.
// POOL=1 (conv2): skip the h2 store entirely; accumulate per-region channel
// sums in registers -> LDS reduce -> global atomics (region_mean fused away).
// ---------------------------------------------------------------------------
#define EDGE_ISSUE(SRCR, V0, V1)                                             \
    _Pragma("unroll")                                                        \
    for (int mt = 0; mt < 4; ++mt) {                                         \
        int s_ = __shfl(SRCR, mt * 16 + m);                                  \
        const u32x4* vp = (const u32x4*)(V + (size_t)s_ * HDIM + quad * 8);  \
        V0[mt] = vp[0]; V1[mt] = vp[4];                                      \
    }

#define EDGE_FOLD(V0, V1, OFF)                                                     \
    _Pragma("unroll")                                                              \
    for (int mt = 0; mt < 4; ++mt) {                                               \
        int urow = wave * 16 + (OFF) + mt;                                         \
        u32x4 u0 = *(const u32x4*)((const char*)Ush + urow * 128 + quad * 16);     \
        u32x4 u1 = *(const u32x4*)((const char*)Ush + urow * 128 + 64 + quad * 16);\
        u32x4 a0, a1;                                                              \
        _Pragma("unroll")                                                          \
        for (int p = 0; p < 4; ++p) {                                              \
            a0[p] = addrelu2(u0[p], V0[mt][p]);                                    \
            a1[p] = addrelu2(u1[p], V1[mt][p]);                                    \
        }                                                                          \
        hf8 A0 = __builtin_bit_cast(hf8, a0);                                      \
        hf8 A1 = __builtin_bit_cast(hf8, a1);                                      \
        f32x4 acc[4] = {{0,0,0,0},{0,0,0,0},{0,0,0,0},{0,0,0,0}};                  \
        _Pragma("unroll")                                                          \
        for (int nt = 0; nt < 4; ++nt) {                                           \
            int bb  = nt * 2048 + m * 128 + quad * 16;                             \
            int bs0 = bb ^ ((m & 7) << 4);                                         \
            int bs1 = (bb + 64) ^ ((m & 7) << 4);                                  \
            hf8 Bh0 = *(const hf8*)((const char*)Wsh + bs0);                       \
            hf8 Bl0 = *(const hf8*)((const char*)Wsh + 8192 + bs0);                \
            hf8 Bh1 = *(const hf8*)((const char*)Wsh + bs1);                       \
            hf8 Bl1 = *(const hf8*)((const char*)Wsh + 8192 + bs1);                \
            acc[nt] = __builtin_amdgcn_mfma_f32_16x16x32_f16(A0, Bl0, acc[nt], 0, 0, 0); \
            acc[nt] = __builtin_amdgcn_mfma_f32_16x16x32_f16(A0, Bh0, acc[nt], 0, 0, 0); \
            acc[nt] = __builtin_amdgcn_mfma_f32_16x16x32_f16(A1, Bl1, acc[nt], 0, 0, 0); \
            acc[nt] = __builtin_amdgcn_mfma_f32_16x16x32_f16(A1, Bh1, acc[nt], 0, 0, 0); \
        }                                                                          \
        float mx[4];                                                               \
        _Pragma("unroll")                                                          \
        for (int nt = 0; nt < 4; ++nt)                                             \
            mx[nt] = fmaxf(fmaxf(acc[nt][0], acc[nt][1]), fmaxf(acc[nt][2], acc[nt][3])); \
        _Pragma("unroll")                                                          \
        for (int nt = 0; nt < 4; ++nt) {                                           \
            mx[nt] = fmaxf(mx[nt], __shfl_xor(mx[nt], 16));                        \
            mx[nt] = fmaxf(mx[nt], __shfl_xor(mx[nt], 32));                        \
        }                                                                          \
        float val = (quad == 0) ? mx[0] : (quad == 1) ? mx[1] : (quad == 2) ? mx[2] : mx[3]; \
        float hv = fmaxf(val + b2v, 0.f);                                          \
        if constexpr (POOL) {                                                      \
            int lbl = labels[nb + (OFF) + mt];                                     \
            _Pragma("unroll")                                                      \
            for (int r = 0; r < 8; ++r) pacc[r] += (lbl == r) ? hv : 0.f;          \
        } else {                                                                   \
            out[(size_t)(nb + (OFF) + mt) * HDIM + lane] = f16r(hv);               \
        }                                                                          \
    }

template<int POOL>
__global__ __launch_bounds__(256, 3) void edge_mfma_kernel(
    const unsigned short* __restrict__ U, const unsigned short* __restrict__ V,
    const int* __restrict__ src,
    const unsigned short* __restrict__ Whi, const unsigned short* __restrict__ Wlo,
    const float* __restrict__ b2, unsigned short* __restrict__ out,
    const int* __restrict__ labels, float* __restrict__ qsums, int N)
{
    __shared__ __align__(16) unsigned short Wsh[8192];   // 16 KB: hi @0, lo @8192B
    __shared__ __align__(16) unsigned short Ush[4096];   // 8 KB: 64 U rows

    int tid  = threadIdx.x;
    int wave = tid >> 6;
    int lane = tid & 63;
    int quad = lane >> 4;
    int m    = lane & 15;

    int nbB = blockIdx.x * 64;           // block node base
    int nb  = nbB + wave * 16;           // wave's 16 nodes (4 tiles)
    bool act = nb < N;                   // N % 16 == 0 -> all-or-nothing per wave

    // ---- stage W2 hi/lo into LDS with row-XOR swizzle ------------------
#pragma unroll
    for (int it = 0; it < 4; ++it) {
        int chunk = it * 256 + tid;
        int reg   = it >> 1;                  // it 0,1 -> hi ; 2,3 -> lo
        int b     = (chunk & 511) * 16;
        int bs    = b ^ (((b >> 7) & 7) << 4);
        const unsigned short* sp = reg ? Wlo : Whi;
        u32x4 d = *(const u32x4*)((const char*)sp + b);
        *(u32x4*)((char*)Wsh + reg * 8192 + bs) = d;
    }
    // ---- stage block's 64 U rows (contiguous 8 KB) ---------------------
#pragma unroll
    for (int it = 0; it < 2; ++it) {
        int ofs = (it * 256 + tid) * 16;
        *(u32x4*)((char*)Ush + ofs) =
            *(const u32x4*)((const char*)(U + (size_t)nbB * HDIM) + ofs);
    }

    int srcA = 0, srcB = 0, srcC = 0, srcD = 0;
    if (act) {
        srcA = src[(size_t)(nb + 0)  * 16 + lane];
        srcB = src[(size_t)(nb + 4)  * 16 + lane];
        srcC = src[(size_t)(nb + 8)  * 16 + lane];
        srcD = src[(size_t)(nb + 12) * 16 + lane];
    }
    float b2v = b2[lane];
    float pacc[8] = {0, 0, 0, 0, 0, 0, 0, 0};

    __syncthreads();     // drains everything; placed BEFORE gather issue

    if (act) {
        u32x4 vA0[4], vA1[4], vB0[4], vB1[4];
        u32x4 vC0[4], vC1[4], vD0[4], vD1[4];
        EDGE_ISSUE(srcA, vA0, vA1)
        EDGE_ISSUE(srcB, vB0, vB1)
        EDGE_FOLD(vA0, vA1, 0)
        EDGE_ISSUE(srcC, vC0, vC1)
        EDGE_FOLD(vB0, vB1, 4)
        EDGE_ISSUE(srcD, vD0, vD1)
        EDGE_FOLD(vC0, vC1, 8)
        EDGE_FOLD(vD0, vD1, 12)
    }

    if constexpr (POOL) {
        float* ls = (float*)Ush;            // reuse U staging as 512-f32 buffer
        __syncthreads();                    // all waves done reading Ush
        for (int idx = tid; idx < 512; idx += 256) ls[idx] = 0.f;
        __syncthreads();
#pragma unroll
        for (int r = 0; r < 8; ++r) atomicAdd(&ls[r * 64 + lane], pacc[r]);
        __syncthreads();
        for (int idx = tid; idx < 512; idx += 256) atomicAdd(&qsums[idx], ls[idx]);
    }
}

// ---------------------------------------------------------------------------
// tail: fully parallel quotient convs (8 nodes, 32 edges) + pool + linear.
// ---------------------------------------------------------------------------
#define EQ_MAX 64
__global__ void tail_kernel(const float* __restrict__ qsums, const int* __restrict__ qcnt,
                            const int* __restrict__ qei, int Eq,
                            const float* __restrict__ W31, const float* __restrict__ b31,
                            const float* __restrict__ W32, const float* __restrict__ b32,
                            const float* __restrict__ W41, const float* __restrict__ b41,
                            const float* __restrict__ W42, const float* __restrict__ b42,
                            const float* __restrict__ linW, const float* __restrict__ linb,
                            float* __restrict__ out)
{
    __shared__ float qx[512], uu[512], vv[512];
    __shared__ float hr[EQ_MAX * 64], me[EQ_MAX * 64];
    __shared__ __align__(16) float W2s[64 * 64];
    __shared__ int   qes[EQ_MAX], qet[EQ_MAX];
    __shared__ float emb[64];

    int tid = threadIdx.x;
    if (Eq > EQ_MAX) Eq = EQ_MAX;

    if (tid < Eq) { qes[tid] = qei[tid]; qet[tid] = qei[Eq + tid]; }
    for (int idx = tid; idx < 512; idx += 256) {
        int r = idx >> 6;
        int cc = qcnt[r];
        qx[idx] = (cc > 0) ? qsums[idx] / (float)cc : 0.f;
    }
    __syncthreads();

    for (int layer = 0; layer < 2; ++layer) {
        const float* W1p = layer ? W41 : W31;
        const float* b1p = layer ? b41 : b31;
        const float* W2p = layer ? W42 : W32;
        const float* b2p = layer ? b42 : b32;

        for (int idx = tid * 4; idx < 4096; idx += 1024)
            *(fv4*)&W2s[idx] = *(const fv4*)&W2p[idx];

        for (int idx = tid; idx < 512; idx += 256) {
            int t = idx >> 6, c = idx & 63;
            float su = 0.f, sv = 0.f;
#pragma unroll 8
            for (int d = 0; d < 64; ++d) {
                float hv = qx[t * 64 + d];
                float a = W1p[d * 64 + c];
                float b = W1p[(d + 64) * 64 + c];
                su += hv * (a - b);
                sv += hv * b;
            }
            uu[idx] = su + b1p[c];
            vv[idx] = sv;
        }
        __syncthreads();

        for (int idx = tid; idx < Eq * 64; idx += 256) {
            int e = idx >> 6, c = idx & 63;
            hr[idx] = fmaxf(uu[qet[e] * 64 + c] + vv[qes[e] * 64 + c], 0.f);
        }
        __syncthreads();

        {
            int c = tid & 63, e0 = tid >> 6;
            for (int e = e0; e < Eq; e += 4) {
                float acc = 0.f;
#pragma unroll 8
                for (int j = 0; j < 64; ++j)
                    acc += hr[e * 64 + j] * W2s[j * 64 + c];
                me[e * 64 + c] = acc;
            }
        }
        __syncthreads();

        for (int idx = tid; idx < 512; idx += 256) {
            int t = idx >> 6, c = idx & 63;
            float a = -INFINITY;
            for (int e = 0; e < Eq; ++e)
                if (qet[e] == t) a = fmaxf(a, me[e * 64 + c]);
            float vout = (a == -INFINITY) ? 0.f : (a + b2p[c]);
            qx[idx] = fmaxf(vout, 0.f);
        }
        __syncthreads();
    }

    if (tid < 64) {
        float s = 0.f;
        for (int r = 0; r < 8; ++r) s += qx[r * 64 + tid];
        emb[tid] = s;
    }
    __syncthreads();
    if (tid < 8) {
        float o = linb[tid];
        for (int c = 0; c < 64; ++c) o += emb[c] * linW[c * 8 + tid];
        out[tid] = o;
    }
}

// ---------------------------------------------------------------------------
extern "C" void kernel_launch(void* const* d_in, const int* in_sizes, int n_in,
                              void* d_out, int out_size, void* d_ws, size_t ws_size,
                              hipStream_t stream)
{
    const float* x    = (const float*)d_in[0];
    const float* pos  = (const float*)d_in[1];
    const int*   ei   = (const int*)d_in[2];
    const int*   lbl  = (const int*)d_in[3];
    const int*   qei  = (const int*)d_in[4];
    const float* W11 = (const float*)d_in[5];
    const float* b11 = (const float*)d_in[6];
    const float* W12 = (const float*)d_in[7];
    const float* b12 = (const float*)d_in[8];
    const float* W21 = (const float*)d_in[9];
    const float* b21 = (const float*)d_in[10];
    const float* W22 = (const float*)d_in[11];
    const float* b22 = (const float*)d_in[12];
    const float* W31 = (const float*)d_in[13];
    const float* b31 = (const float*)d_in[14];
    const float* W32 = (const float*)d_in[15];
    const float* b32 = (const float*)d_in[16];
    const float* W41 = (const float*)d_in[17];
    const float* b41 = (const float*)d_in[18];
    const float* W42 = (const float*)d_in[19];
    const float* b42 = (const float*)d_in[20];
    const float* linW = (const float*)d_in[21];
    const float* linb = (const float*)d_in[22];

    int N  = in_sizes[0] / 16;          // 100000
    int Eq = in_sizes[4] / 2;           // 32
    const int* src = ei;                // row 0 = src; tgt = repeat(arange(N),16)

    size_t NH = (size_t)N * HDIM;
    unsigned short* hbf = (unsigned short*)d_ws;   // fp16 N*64 (h1)
    unsigned short* Ub  = hbf + NH;                // fp16 N*64
    unsigned short* Vb  = Ub + NH;                 // fp16 N*64
    unsigned short* w2h1 = Vb + NH;
    unsigned short* w2l1 = w2h1 + 4096;
    unsigned short* w2h2 = w2l1 + 4096;
    unsigned short* w2l2 = w2h2 + 4096;
    unsigned short* wph  = w2l2 + 4096;            // 8192
    unsigned short* wpl  = wph + 8192;             // 8192
    float* qsums = (float*)(wpl + 8192);
    int*   qcnt  = (int*)(qsums + 512);

    (void)hipMemsetAsync(qsums, 0, 512 * sizeof(float) + 8 * sizeof(int), stream);

    int nTiles      = N / 16;           // pre_mfma tiles (6250)
    int edgeBlocks  = (N + 63) / 64;    // edge blocks, 64 nodes each (1563)
    int mainBlocks  = 2048;

    // conv1 (pre1 + fused prep + label histogram)
    pre1_kernel<<<mainBlocks + 32, 256, 0, stream>>>(
        x, pos, W11, b11, Ub, Vb, N, mainBlocks,
        W12, W22, W21, w2h1, w2l1, w2h2, w2l2, wph, wpl, lbl, qcnt);
    edge_mfma_kernel<0><<<edgeBlocks, 256, 0, stream>>>(
        Ub, Vb, src, w2h1, w2l1, b12, hbf, lbl, qsums, N);
    // conv2
    pre_mfma_kernel<<<1563, 256, 0, stream>>>(hbf, wph, wpl, b21, Ub, Vb, nTiles);
    // conv2 edge + fused region-sum pooling (h2 never materialized)
    edge_mfma_kernel<1><<<edgeBlocks, 256, 0, stream>>>(
        Ub, Vb, src, w2h2, w2l2, b22, hbf, lbl, qsums, N);
    // quotient tail
    tail_kernel<<<1, 256, 0, stream>>>(qsums, qcnt, qei, Eq,
                                       W31, b31, W32, b32,
                                       W41, b41, W42, b42,
                                       linW, linb, (float*)d_out);
}